// Round 3
// baseline (218.798 us; speedup 1.0000x reference)
//
#include <hip/hip_runtime.h>
#include <hip/hip_bf16.h>

#define Ls 256
#define Kk 9
#define Bb 512

typedef short s16x8 __attribute__((ext_vector_type(8)));
typedef float f32x4 __attribute__((ext_vector_type(4)));

__device__ __forceinline__ unsigned short f2bf(float f) {
    __hip_bfloat16 h = __float2bfloat16(f);
    return *reinterpret_cast<unsigned short*>(&h);
}

// XOR swizzle: spreads 16 consecutive rows 2-way (free) on reads AND makes
// row-groups {c,c+4,c+8,c+12} (epilogue b16 stores) hit 4 distinct 16B slots.
#define SWZ(row) (((((row)&7)<<4)) ^ ((((row)&8))<<2))

// ---- weight prep: pack w1/w2/w3/wd into bf16 MFMA B-fragments ----
// lane l of frag: k = kc*32 + (l>>4)*8 + j , n = nt*16 + (l&15).
// conv1: frags 0..47 (KC=4,NT=4); conv2: 48..95 (KC=2,NT=8); conv3: 96..191 (KC=4,NT=8);
// dense wd: 192..195 (KC=kc, N=16 zero-padded past 9).
__global__ __launch_bounds__(256) void kw_prep(
    const float* __restrict__ w1, const float* __restrict__ w2, const float* __restrict__ w3,
    const float* __restrict__ wd, uint4* __restrict__ wfrag)
{
    const int gid = blockIdx.x * 256 + threadIdx.x;
    const int frag = gid >> 6;
    const int lane = gid & 63;
    if (frag >= 196) return;
    const int kb = (lane >> 4) * 8;
    const int nl = lane & 15;
    float v[8];
    if (frag < 48) {
        int nt = frag & 3, kc = (frag >> 2) & 3, t = frag >> 4;
        int n = nt * 16 + nl;
        #pragma unroll
        for (int j = 0; j < 8; ++j) v[j] = w1[(t * 128 + kc * 32 + kb + j) * 64 + n];
    } else if (frag < 96) {
        int f = frag - 48; int nt = f & 7, kc = (f >> 3) & 1, t = f >> 4;
        int n = nt * 16 + nl;
        #pragma unroll
        for (int j = 0; j < 8; ++j) v[j] = w2[(t * 64 + kc * 32 + kb + j) * 128 + n];
    } else if (frag < 192) {
        int f = frag - 96; int nt = f & 7, kc = (f >> 3) & 3, t = f >> 5;
        int n = nt * 16 + nl;
        #pragma unroll
        for (int j = 0; j < 8; ++j) v[j] = w3[(t * 128 + kc * 32 + kb + j) * 128 + n];
    } else {
        int kc = frag - 192;
        #pragma unroll
        for (int j = 0; j < 8; ++j) v[j] = (nl < Kk) ? wd[(kc * 32 + kb + j) * Kk + nl] : 0.f;
    }
    uint4 o;
    o.x = (unsigned)f2bf(v[0]) | ((unsigned)f2bf(v[1]) << 16);
    o.y = (unsigned)f2bf(v[2]) | ((unsigned)f2bf(v[3]) << 16);
    o.z = (unsigned)f2bf(v[4]) | ((unsigned)f2bf(v[5]) << 16);
    o.w = (unsigned)f2bf(v[6]) | ((unsigned)f2bf(v[7]) << 16);
    wfrag[frag * 64 + lane] = o;
}

// ---- fused embed + conv1 + conv2 + conv3(dil2) + dense(MFMA) ----
// E (bf16, 82 rows x 256B, row=i+1) aliased by X2 (80 rows, row=i)
// X1 (bf16, 82 rows x 128B, row=i+1)  aliased by X3 (bf16, 64 rows x 256B, row=p)
#define X1_OFF  20992
#define X3_OFF  20992
#define SMEM_BYTES (20992 + 64 * 256)   // 37376 -> 4 blocks/CU

__global__ __launch_bounds__(256, 4) void kmain(
    const int* __restrict__ text, const float* __restrict__ embed,
    const uint4* __restrict__ wfrag,
    const float* __restrict__ b1, const float* __restrict__ b2, const float* __restrict__ b3,
    const float* __restrict__ bd,
    float* __restrict__ logits)
{
    __shared__ __align__(16) char smem[SMEM_BYTES];
    const int b = blockIdx.y, l0 = blockIdx.x * 64;
    const int tid = threadIdx.x;
    const int lane = tid & 63, wv = tid >> 6;
    const int nl = lane & 15, kg = lane >> 4;

    // zero pad rows: E rows 0,81 ; X1 rows 0,81
    for (int it = tid; it < 96; it += 256) {
        char* p;
        if (it < 32)       p = smem + it * 8;
        else if (it < 64)  p = smem + 81 * 256 + (it - 32) * 8;
        else if (it < 80)  p = smem + X1_OFF + (it - 64) * 8;
        else               p = smem + X1_OFF + 81 * 128 + (it - 80) * 8;
        *(uint2*)p = make_uint2(0u, 0u);
    }
    // stage embed rows (pos l0-8 .. l0+71) as bf16, swizzled
    for (int it = tid; it < 80 * 32; it += 256) {
        const int row = (it >> 5) + 1;      // 1..80
        const int c4  = it & 31;
        const int pos = l0 - 9 + row;
        uint2 val = make_uint2(0u, 0u);
        if (pos >= 0 && pos < Ls) {
            const int tok = text[b * Ls + pos];
            const float4 e = ((const float4*)embed)[tok * 32 + c4];
            val.x = (unsigned)f2bf(e.x) | ((unsigned)f2bf(e.y) << 16);
            val.y = (unsigned)f2bf(e.z) | ((unsigned)f2bf(e.w) << 16);
        }
        int addr = row * 256 + c4 * 8;
        addr ^= SWZ(row);
        *(uint2*)(smem + addr) = val;
    }
    __syncthreads();

    // ---- conv1: M=80(5 tiles), N=64 (ntile = wv), K=3 x 128
    {
        f32x4 acc[5];
        #pragma unroll
        for (int mt = 0; mt < 5; ++mt) acc[mt] = (f32x4)0.f;
        #pragma unroll
        for (int t = 0; t < 3; ++t) {
            #pragma unroll
            for (int kc = 0; kc < 4; ++kc) {
                const s16x8 bf = *(const s16x8*)(wfrag + ((t * 4 + kc) * 4 + wv) * 64 + lane);
                #pragma unroll
                for (int mt = 0; mt < 5; ++mt) {
                    const int row = mt * 16 + nl + t;
                    int addr = row * 256 + kc * 64 + kg * 16;
                    addr ^= SWZ(row);
                    const s16x8 a = *(const s16x8*)(smem + addr);
                    acc[mt] = __builtin_amdgcn_mfma_f32_16x16x32_bf16(a, bf, acc[mt], 0, 0, 0);
                }
            }
        }
        const float bias = b1[wv * 16 + nl];
        #pragma unroll
        for (int mt = 0; mt < 5; ++mt) {
            #pragma unroll
            for (int r = 0; r < 4; ++r) {
                const int i = mt * 16 + kg * 4 + r;
                const int pos = l0 - 8 + i;
                float v = fmaxf(acc[mt][r] + bias, 0.f);
                if (pos < 0 || pos >= Ls) v = 0.f;
                const int row = i + 1;
                int addr = X1_OFF + row * 128 + (wv * 16 + nl) * 2;
                addr ^= SWZ(row);
                *(unsigned short*)(smem + addr) = f2bf(v);
            }
        }
    }
    __syncthreads();

    // ---- conv2: M=80, N=128 (ntiles wv, wv+4), K=3 x 64
    {
        f32x4 acc[5][2];
        #pragma unroll
        for (int mt = 0; mt < 5; ++mt) { acc[mt][0] = (f32x4)0.f; acc[mt][1] = (f32x4)0.f; }
        #pragma unroll
        for (int t = 0; t < 3; ++t) {
            #pragma unroll
            for (int kc = 0; kc < 2; ++kc) {
                const s16x8 bf0 = *(const s16x8*)(wfrag + (48 + (t * 2 + kc) * 8 + wv) * 64 + lane);
                const s16x8 bf1 = *(const s16x8*)(wfrag + (48 + (t * 2 + kc) * 8 + wv + 4) * 64 + lane);
                #pragma unroll
                for (int mt = 0; mt < 5; ++mt) {
                    const int row = mt * 16 + nl + t;
                    int addr = X1_OFF + row * 128 + kc * 64 + kg * 16;
                    addr ^= SWZ(row);
                    const s16x8 a = *(const s16x8*)(smem + addr);
                    acc[mt][0] = __builtin_amdgcn_mfma_f32_16x16x32_bf16(a, bf0, acc[mt][0], 0, 0, 0);
                    acc[mt][1] = __builtin_amdgcn_mfma_f32_16x16x32_bf16(a, bf1, acc[mt][1], 0, 0, 0);
                }
            }
        }
        const float bs0 = b2[wv * 16 + nl], bs1 = b2[(wv + 4) * 16 + nl];
        #pragma unroll
        for (int mt = 0; mt < 5; ++mt) {
            #pragma unroll
            for (int r = 0; r < 4; ++r) {
                const int i = mt * 16 + kg * 4 + r;
                const int pos = l0 - 8 + i;
                float v0 = fmaxf(acc[mt][0][r] + bs0, 0.f);
                float v1 = fmaxf(acc[mt][1][r] + bs1, 0.f);
                if (pos < 0 || pos >= Ls) { v0 = 0.f; v1 = 0.f; }
                const int row = i;
                int a0 = row * 256 + (wv * 16 + nl) * 2;       a0 ^= SWZ(row);
                int a1 = row * 256 + ((wv + 4) * 16 + nl) * 2; a1 ^= SWZ(row);
                *(unsigned short*)(smem + a0) = f2bf(v0);
                *(unsigned short*)(smem + a1) = f2bf(v1);
            }
        }
    }
    __syncthreads();

    // ---- conv3 (dil 2): M=64 (i=8..71), N=128, K=3 x 128; output -> X3 bf16
    {
        f32x4 acc[4][2];
        #pragma unroll
        for (int mt = 0; mt < 4; ++mt) { acc[mt][0] = (f32x4)0.f; acc[mt][1] = (f32x4)0.f; }
        #pragma unroll
        for (int t = 0; t < 3; ++t) {
            #pragma unroll
            for (int kc = 0; kc < 4; ++kc) {
                const s16x8 bf0 = *(const s16x8*)(wfrag + (96 + (t * 4 + kc) * 8 + wv) * 64 + lane);
                const s16x8 bf1 = *(const s16x8*)(wfrag + (96 + (t * 4 + kc) * 8 + wv + 4) * 64 + lane);
                #pragma unroll
                for (int mt = 0; mt < 4; ++mt) {
                    const int row = 6 + mt * 16 + nl + 2 * t;
                    int addr = row * 256 + kc * 64 + kg * 16;
                    addr ^= SWZ(row);
                    const s16x8 a = *(const s16x8*)(smem + addr);
                    acc[mt][0] = __builtin_amdgcn_mfma_f32_16x16x32_bf16(a, bf0, acc[mt][0], 0, 0, 0);
                    acc[mt][1] = __builtin_amdgcn_mfma_f32_16x16x32_bf16(a, bf1, acc[mt][1], 0, 0, 0);
                }
            }
        }
        const float bs0 = b3[wv * 16 + nl], bs1 = b3[(wv + 4) * 16 + nl];
        #pragma unroll
        for (int mt = 0; mt < 4; ++mt) {
            #pragma unroll
            for (int r = 0; r < 4; ++r) {
                const int p = mt * 16 + kg * 4 + r;             // 0..63
                float v0 = fmaxf(acc[mt][0][r] + bs0, 0.f);
                float v1 = fmaxf(acc[mt][1][r] + bs1, 0.f);
                int a0 = X3_OFF + p * 256 + (wv * 16 + nl) * 2;       a0 ^= SWZ(p);
                int a1 = X3_OFF + p * 256 + ((wv + 4) * 16 + nl) * 2; a1 ^= SWZ(p);
                *(unsigned short*)(smem + a0) = f2bf(v0);
                *(unsigned short*)(smem + a1) = f2bf(v1);
            }
        }
    }
    __syncthreads();

    // ---- dense 128 -> 9 via MFMA (N=16 zero-padded); wave wv: rows wv*16..+15
    {
        f32x4 dacc = (f32x4)0.f;
        #pragma unroll
        for (int kc = 0; kc < 4; ++kc) {
            const int row = wv * 16 + nl;
            int addr = X3_OFF + row * 256 + kc * 64 + kg * 16;
            addr ^= SWZ(row);
            const s16x8 a = *(const s16x8*)(smem + addr);
            const s16x8 bf = *(const s16x8*)(wfrag + (192 + kc) * 64 + lane);
            dacc = __builtin_amdgcn_mfma_f32_16x16x32_bf16(a, bf, dacc, 0, 0, 0);
        }
        const float bdv = (nl < Kk) ? bd[nl] : 0.f;
        #pragma unroll
        for (int r = 0; r < 4; ++r) {
            const int p = wv * 16 + kg * 4 + r;
            if (nl < Kk)
                logits[((size_t)b * Ls + l0 + p) * Kk + nl] = dacc[r] + bdv;
        }
    }
}

// ---- CRF: linear-domain forward, one batch-row per lane ----
#define GETF(BUF, fi) __uint_as_float( (((fi)&3)==0) ? BUF[(fi)>>2].x : (((fi)&3)==1) ? BUF[(fi)>>2].y : (((fi)&3)==2) ? BUF[(fi)>>2].z : BUF[(fi)>>2].w )

#define LOADTILE(BUF, k) { \
    _Pragma("unroll") for (int i_ = 0; i_ < 9; ++i_) BUF[i_] = b4[9*(k) + i_]; }

#define STEP(BUF, s, t) { \
    float elg[9], nf[9]; \
    _Pragma("unroll") for (int j_ = 0; j_ < 9; ++j_) elg[j_] = __expf(GETF(BUF, (s)*9 + j_)); \
    _Pragma("unroll") for (int j_ = 0; j_ < 9; ++j_) { \
        float acc_ = f[0] * eT[j_]; \
        _Pragma("unroll") for (int i_ = 1; i_ < 9; ++i_) acc_ = fmaf(f[i_], eT[i_*9+j_], acc_); \
        nf[j_] = acc_ * elg[j_]; } \
    const bool keep_ = (t) < len; \
    _Pragma("unroll") for (int j_ = 0; j_ < 9; ++j_) f[j_] = keep_ ? nf[j_] : f[j_]; }

#define RENORM() { \
    float m_ = fmaxf(fmaxf(fmaxf(fmaxf(f[0],f[1]),fmaxf(f[2],f[3])),fmaxf(fmaxf(f[4],f[5]),fmaxf(f[6],f[7]))),f[8]); \
    C += __logf(m_); \
    const float inv_ = 1.0f / m_; \
    _Pragma("unroll") for (int j_ = 0; j_ < 9; ++j_) f[j_] *= inv_; }

__global__ __launch_bounds__(64, 1) void kc_crf(
    const int* __restrict__ text, const int* __restrict__ labels,
    const float* __restrict__ trans, const float* __restrict__ logits,
    float* __restrict__ lens_out, float* __restrict__ ll_out)
{
    const int blk = blockIdx.x;
    const int lane = threadIdx.x;
    __shared__ float trS[81];
    __shared__ int   lenI[64];
    __shared__ float scoreS[64];
    for (int i = lane; i < 81; i += 64) trS[i] = trans[i];
    __syncthreads();

    // Phase A: cooperative lens + sequence score, one row at a time
    for (int rl = 0; rl < 64; ++rl) {
        const int row = blk * 64 + rl;
        const int4 tx = ((const int4*)(text + (size_t)row * Ls))[lane];
        int c = (tx.x != 0) + (tx.y != 0) + (tx.z != 0) + (tx.w != 0);
        #pragma unroll
        for (int off = 1; off < 64; off <<= 1) c += __shfl_xor(c, off);
        const int len = c;
        const int4 lb = ((const int4*)(labels + (size_t)row * Ls))[lane];
        const int t0 = lane * 4;
        int la[5];
        la[0] = lb.x; la[1] = lb.y; la[2] = lb.z; la[3] = lb.w;
        la[4] = (t0 + 4 < Ls) ? labels[(size_t)row * Ls + t0 + 4] : 0;
        const float* lgrow = logits + (size_t)row * Ls * Kk;
        float s = 0.f;
        #pragma unroll
        for (int q = 0; q < 4; ++q) {
            const int t = t0 + q;
            if (t < len) s += lgrow[t * Kk + la[q]];
            if (t < len - 1) s += trS[la[q] * Kk + la[q + 1]];
        }
        #pragma unroll
        for (int off = 1; off < 64; off <<= 1) s += __shfl_xor(s, off);
        if (lane == 0) { lenI[rl] = len; scoreS[rl] = s; }
    }
    __syncthreads();

    // Phase B: linear-domain forward recurrence, row = blk*64 + lane
    float eT[81];
    #pragma unroll
    for (int i = 0; i < 81; ++i) eT[i] = __expf(trS[i]);

    const int row = blk * 64 + lane;
    const int len = lenI[lane];
    const float score = scoreS[lane];
    lens_out[row] = (float)len;

    const uint4* b4 = (const uint4*)(logits + (size_t)row * Ls * Kk);
    uint4 A[9], Bv[9];
    float f[9];
    float C = 0.f;

    LOADTILE(A, 0)
    #pragma unroll
    for (int j = 0; j < 9; ++j) f[j] = __expf(GETF(A, j));
    LOADTILE(Bv, 1)
    STEP(A, 1, 1) STEP(A, 2, 2) STEP(A, 3, 3) RENORM()

    #pragma unroll 1
    for (int k = 1; k + 1 < 64; k += 2) {
        LOADTILE(A, k + 1)
        STEP(Bv, 0, 4*k+0) STEP(Bv, 1, 4*k+1) STEP(Bv, 2, 4*k+2) STEP(Bv, 3, 4*k+3) RENORM()
        LOADTILE(Bv, k + 2)
        STEP(A, 0, 4*k+4) STEP(A, 1, 4*k+5) STEP(A, 2, 4*k+6) STEP(A, 3, 4*k+7) RENORM()
    }
    STEP(Bv, 0, 252) STEP(Bv, 1, 253) STEP(Bv, 2, 254) STEP(Bv, 3, 255) RENORM()

    float sum = f[0];
    #pragma unroll
    for (int j = 1; j < 9; ++j) sum += f[j];
    const float log_norm = C + __logf(sum);
    ll_out[row] = score - log_norm;
}

extern "C" void kernel_launch(void* const* d_in, const int* in_sizes, int n_in,
                              void* d_out, int out_size, void* d_ws, size_t ws_size,
                              hipStream_t stream) {
    const int*   text   = (const int*)d_in[0];
    const int*   labels = (const int*)d_in[1];
    const float* embed  = (const float*)d_in[2];
    const float* w1 = (const float*)d_in[3];
    const float* b1 = (const float*)d_in[4];
    const float* w2 = (const float*)d_in[5];
    const float* b2 = (const float*)d_in[6];
    const float* w3 = (const float*)d_in[7];
    const float* b3 = (const float*)d_in[8];
    const float* wd = (const float*)d_in[9];
    const float* bd = (const float*)d_in[10];
    const float* trans = (const float*)d_in[11];

    float* out      = (float*)d_out;
    float* logits   = out;
    float* lens_out = out + (size_t)Bb * Ls * Kk;
    float* ll_out   = lens_out + Bb;
    uint4* wfrag    = (uint4*)d_ws;     // 196 frags x 1KB

    hipLaunchKernelGGL(kw_prep, dim3(49), dim3(256), 0, stream, w1, w2, w3, wd, wfrag);
    hipLaunchKernelGGL(kmain, dim3(Ls / 64, Bb), dim3(256), 0, stream,
                       text, embed, wfrag, b1, b2, b3, bd, logits);
    hipLaunchKernelGGL(kc_crf, dim3(Bb / 64), dim3(64), 0, stream,
                       text, labels, trans, logits, lens_out, ll_out);
}